// Round 2
// baseline (310.629 us; speedup 1.0000x reference)
//
#include <hip/hip_runtime.h>

// DEPTree on gfx950 — bf16 MFMA GEMM with device-side bucketing by matrix id.
// K=4, LEVELS=8, N=21845, D=128, NUM_POS=18, NUM_DEP=46
// ls[l] = (4^l-1)/3: 0,1,5,21,85,341,1365,5461 ; level 7 rows: 5461..21844

#define DD 128
#define NN 21845
#define NPOS 18
#define NDEP 46
#define NCH 21844   // total children over levels 0..6 (4+16+...+16384)

typedef __attribute__((ext_vector_type(8))) short short8;
typedef __attribute__((ext_vector_type(4))) float f32x4;

__device__ __forceinline__ unsigned short f2bf(float f) {
    union { float f; unsigned int u; } v; v.f = f;
    unsigned int r = v.u + 0x7fffu + ((v.u >> 16) & 1u);   // RNE
    return (unsigned short)(r >> 16);
}
__device__ __forceinline__ float bf2f(unsigned short s) {
    union { unsigned int u; float f; } v; v.u = ((unsigned int)s) << 16;
    return v.f;
}

// ---------------- W convert + transpose: Wt[mat][n][k] = bf16(W[mat][k][n]) ----
// mats 0..17 = pos_W, 18..63 = dep_W. grid = 64 mats * 4 (64x64 tiles), block 256.
__global__ __launch_bounds__(256) void convert_kernel(
        const float* __restrict__ posW, const float* __restrict__ depW,
        unsigned short* __restrict__ Wt) {
    int mat = blockIdx.x >> 2;
    int tile = blockIdx.x & 3;
    int tk = (tile >> 1) * 64, tn = (tile & 1) * 64;
    const float* W = (mat < NPOS) ? (posW + (size_t)mat * DD * DD)
                                  : (depW + (size_t)(mat - NPOS) * DD * DD);
    unsigned short* O = Wt + (size_t)mat * DD * DD;
    __shared__ unsigned short lds[64][72];
    int tx = threadIdx.x & 63, ty = threadIdx.x >> 6;
#pragma unroll
    for (int i = 0; i < 16; ++i) {
        int r = ty + i * 4;                       // k within tile
        lds[tx][r] = f2bf(W[(size_t)(tk + r) * DD + tn + tx]);
    }
    __syncthreads();
#pragma unroll
    for (int i = 0; i < 16; ++i) {
        int r = ty + i * 4;                       // n within tile
        O[(size_t)(tn + r) * DD + tk + tx] = lds[r][tx];
    }
}

// ---------------- plan: histogram / scan+tables / scatter ----------------
// cnt layout: [0..17] pos buckets, [18 + l*46 + d] dep buckets for parent level l
__global__ void hist_kernel(const int* __restrict__ pos_ids,
                            const int* __restrict__ dep_ids, int* __restrict__ cnt) {
    int i = blockIdx.x * blockDim.x + threadIdx.x;
    if (i < NN) {
        atomicAdd(&cnt[pos_ids[i]], 1);
    } else if (i < NN + NCH) {
        int j = i - NN;
        int l = 0, base = 0, sz = 4;
        while (j >= base + sz) { base += sz; sz <<= 2; ++l; }
        int c = j - base;                         // child local index at level l
        int did = dep_ids[base + 1 + c];          // ls[l+1] = base+1
        atomicAdd(&cnt[NPOS + l * NDEP + did], 1);
    }
}

__global__ void scan_kernel(const int* __restrict__ cnt, int* __restrict__ cur,
                            int* __restrict__ ntiles, int2* __restrict__ tbl1,
                            int2* __restrict__ tblL) {
    int w = threadIdx.x >> 6;
    int lane = threadIdx.x & 63;
    if (lane != 0) return;
    if (w == 0) {
        int off = 0, t = 0;
        for (int b = 0; b < NPOS; ++b) {
            int c = cnt[b];
            cur[b] = off;
            for (int rs = 0; rs < c; rs += 64) {
                int rr = min(64, c - rs);
                tbl1[t].x = b | (rr << 8);
                tbl1[t].y = off + rs;
                ++t;
            }
            off += c;
        }
        ntiles[0] = t;
    } else {
        int l = w - 1;
        const int baseTab[7] = {0, 4, 20, 84, 340, 1364, 5460}; // ls[l+1]-1
        int base = baseTab[l];
        int off = 0, t = 0;
        int2* tb = tblL + l * 302;
        for (int b = 0; b < NDEP; ++b) {
            int c = cnt[NPOS + l * NDEP + b];
            cur[NPOS + l * NDEP + b] = base + off;
            for (int rs = 0; rs < c; rs += 64) {
                int rr = min(64, c - rs);
                tb[t].x = b | (rr << 8);
                tb[t].y = base + off + rs;
                ++t;
            }
            off += c;
        }
        ntiles[1 + l] = t;
    }
}

__global__ void scatter_kernel(const int* __restrict__ pos_ids,
                               const int* __restrict__ dep_ids, int* __restrict__ cur,
                               int* __restrict__ perm_pos, int* __restrict__ perm_dep) {
    int i = blockIdx.x * blockDim.x + threadIdx.x;
    if (i < NN) {
        int idx = atomicAdd(&cur[pos_ids[i]], 1);
        perm_pos[idx] = i;
    } else if (i < NN + NCH) {
        int j = i - NN;
        int l = 0, base = 0, sz = 4;
        while (j >= base + sz) { base += sz; sz <<= 2; ++l; }
        int c = j - base;
        int did = dep_ids[base + 1 + c];
        int idx = atomicAdd(&cur[NPOS + l * NDEP + did], 1);
        perm_dep[idx] = c;
    }
}

// ---------------- GEMM: 64-row tile x N=128, K=128, 4 waves x (16 rows, 8 n-tiles)
// MODE 0: A = bf16(emb[perm_pos[r]])  (fp32 gather+convert), out = x_bf16[node]
// MODE 1: A = x_bf16[ls_child + perm[r]],                   out = u[c]
// MODE 2: A = max(x_bf16[ls_child + c], u_prev[4c+j] j=0..3), out = u[c]
template <int MODE>
__global__ __launch_bounds__(256) void gemm_kernel(
        const int2* __restrict__ tbl, const int* __restrict__ ntp,
        const int* __restrict__ perm, const unsigned short* __restrict__ Wt,
        const float* __restrict__ bias, const float* __restrict__ embf,
        const unsigned short* __restrict__ xb, const unsigned short* __restrict__ uprev,
        unsigned short* __restrict__ outr) {
    int nt = ntp[0];
    if ((int)blockIdx.x >= nt) return;
    int2 e = tbl[blockIdx.x];
    int bucket = e.x & 255;
    int rows = e.x >> 8;
    int rowstart = e.y;
    int lane = threadIdx.x & 63;
    int w = threadIdx.x >> 6;
    int lr = lane & 15;           // A-row / B-col / D-col within 16-tile
    int kk = (lane >> 4) * 8;     // k slice

    const short8 zero8 = {0, 0, 0, 0, 0, 0, 0, 0};

    int m_a = w * 16 + lr;
    bool valid_a = m_a < rows;
    int rid_a = valid_a ? perm[rowstart + m_a] : 0;

    short8 afr[4];
    if (MODE == 0) {
        const float* ar = embf + (size_t)rid_a * DD + kk;
#pragma unroll
        for (int s = 0; s < 4; ++s) {
            float4 lo = *(const float4*)(ar + s * 32);
            float4 hi = *(const float4*)(ar + s * 32 + 4);
            short8 a;
            a[0] = (short)f2bf(lo.x); a[1] = (short)f2bf(lo.y);
            a[2] = (short)f2bf(lo.z); a[3] = (short)f2bf(lo.w);
            a[4] = (short)f2bf(hi.x); a[5] = (short)f2bf(hi.y);
            a[6] = (short)f2bf(hi.z); a[7] = (short)f2bf(hi.w);
            afr[s] = valid_a ? a : zero8;
        }
    } else if (MODE == 1) {
        const unsigned short* ar = xb + (size_t)rid_a * DD + kk;
#pragma unroll
        for (int s = 0; s < 4; ++s)
            afr[s] = valid_a ? *(const short8*)(ar + s * 32) : zero8;
    } else {
        const unsigned short* xr = xb + (size_t)rid_a * DD + kk;
        const unsigned short* ur = uprev + (size_t)(4 * rid_a) * DD + kk;
#pragma unroll
        for (int s = 0; s < 4; ++s) {
            short8 a = *(const short8*)(xr + s * 32);
#pragma unroll
            for (int j = 0; j < 4; ++j) {
                short8 u = *(const short8*)(ur + j * DD + s * 32);
#pragma unroll
                for (int q = 0; q < 8; ++q)
                    if ((unsigned short)u[q] > (unsigned short)a[q]) a[q] = u[q];
            }
            afr[s] = valid_a ? a : zero8;
        }
    }

    f32x4 acc[8];
#pragma unroll
    for (int t = 0; t < 8; ++t) acc[t] = (f32x4){0.f, 0.f, 0.f, 0.f};

    const unsigned short* Wb = Wt + (size_t)bucket * DD * DD;
#pragma unroll
    for (int s = 0; s < 4; ++s) {
        short8 bfr[8];
#pragma unroll
        for (int t = 0; t < 8; ++t)
            bfr[t] = *(const short8*)(Wb + (size_t)(t * 16 + lr) * DD + s * 32 + kk);
#pragma unroll
        for (int t = 0; t < 8; ++t)
            acc[t] = __builtin_amdgcn_mfma_f32_16x16x32_bf16(afr[s], bfr[t], acc[t], 0, 0, 0);
    }

    // epilogue: D row = (lane>>4)*4+q, col = t*16 + (lane&15)
    int rq[4]; bool vq[4];
#pragma unroll
    for (int q = 0; q < 4; ++q) {
        int m = w * 16 + (lane >> 4) * 4 + q;
        vq[q] = m < rows;
        rq[q] = vq[q] ? perm[rowstart + m] : 0;
    }
    const float* bb = bias + bucket * DD;
#pragma unroll
    for (int t = 0; t < 8; ++t) {
        int col = t * 16 + lr;
        float bv = bb[col];
#pragma unroll
        for (int q = 0; q < 4; ++q) {
            if (vq[q]) {
                float v = fmaxf(acc[t][q] + bv, 0.f);
                outr[(size_t)rq[q] * DD + col] = f2bf(v);
            }
        }
    }
}

// ---------------- final: out = max(x[0], u0 rows 0..3) ----------------
__global__ void final_kernel(const unsigned short* __restrict__ xb,
                             const unsigned short* __restrict__ u0,
                             float* __restrict__ out) {
    int e = threadIdx.x;
    unsigned short m = xb[e];
#pragma unroll
    for (int j = 0; j < 4; ++j) {
        unsigned short u = u0[j * DD + e];
        if (u > m) m = u;
    }
    out[e] = bf2f(m);
}

extern "C" void kernel_launch(void* const* d_in, const int* in_sizes, int n_in,
                              void* d_out, int out_size, void* d_ws, size_t ws_size,
                              hipStream_t stream) {
    const float* emb     = (const float*)d_in[0];
    const int*   pos_ids = (const int*)d_in[1];
    const int*   dep_ids = (const int*)d_in[2];
    const float* pos_W   = (const float*)d_in[3];
    const float* pos_b   = (const float*)d_in[4];
    const float* dep_W   = (const float*)d_in[5];
    const float* dep_b   = (const float*)d_in[6];
    float* out = (float*)d_out;

    char* p = (char*)d_ws;
    auto alloc = [&](size_t bytes) {
        char* r = p; p += (bytes + 255) & ~(size_t)255; return r;
    };
    unsigned short* xbf = (unsigned short*)alloc((size_t)NN * DD * 2);     // 5.6 MB
    unsigned short* uA  = (unsigned short*)alloc((size_t)16384 * DD * 2);  // 4 MB
    unsigned short* uB  = (unsigned short*)alloc((size_t)4096 * DD * 2);   // 1 MB
    unsigned short* Wt  = (unsigned short*)alloc((size_t)64 * DD * DD * 2);// 2 MB
    int*  cnt      = (int*)alloc(340 * 4);
    int*  cur      = (int*)alloc(340 * 4);
    int*  ntiles   = (int*)alloc(8 * 4);
    int*  perm_pos = (int*)alloc((size_t)NN * 4);
    int*  perm_dep = (int*)alloc((size_t)NCH * 4);
    int2* tbl1     = (int2*)alloc(360 * 8);
    int2* tblL     = (int2*)alloc(7 * 302 * 8);

    hipMemsetAsync(cnt, 0, 340 * 4, stream);
    convert_kernel<<<256, 256, 0, stream>>>(pos_W, dep_W, Wt);
    hist_kernel<<<171, 256, 0, stream>>>(pos_ids, dep_ids, cnt);
    scan_kernel<<<1, 512, 0, stream>>>(cnt, cur, ntiles, tbl1, tblL);
    scatter_kernel<<<171, 256, 0, stream>>>(pos_ids, dep_ids, cur, perm_pos, perm_dep);

    // stage1: x = relu(emb @ pos_W[pid] + pos_b[pid]) -> bf16
    gemm_kernel<0><<<360, 256, 0, stream>>>(tbl1, ntiles + 0, perm_pos, Wt, pos_b,
                                            emb, nullptr, nullptr, xbf);

    const unsigned short* Wtd = Wt + (size_t)NPOS * DD * DD;
    // parent level 6: A = x rows of level 7 (ls[7]=5461)
    gemm_kernel<1><<<302, 256, 0, stream>>>(tblL + 6 * 302, ntiles + 7, perm_dep, Wtd,
                                            dep_b, nullptr, xbf + (size_t)5461 * DD,
                                            nullptr, uA);
    // parent levels 5..0: A = max(x[ls[l+1]+c], uprev[4c+j])
    const int ls_c[7]  = {1, 5, 21, 85, 341, 1365, 5461}; // ls[l+1]
    const int grids[7] = {4, 16, 47, 50, 62, 110, 302};
    unsigned short* uin = uA;
    unsigned short* uout = uB;
    for (int l = 5; l >= 0; --l) {
        gemm_kernel<2><<<grids[l], 256, 0, stream>>>(tblL + l * 302, ntiles + 1 + l,
                                                     perm_dep, Wtd, dep_b, nullptr,
                                                     xbf + (size_t)ls_c[l] * DD, uin, uout);
        unsigned short* t = uin; uin = uout; uout = t;
    }
    // uin now holds u of parent level 0 (4 rows)
    final_kernel<<<1, 128, 0, stream>>>(xbf, uin, out);
}

// Round 3
// 201.220 us; speedup vs baseline: 1.5437x; 1.5437x over previous
//
#include <hip/hip_runtime.h>

// DEPTree on gfx950 — bf16 MFMA GEMM with device-side bucketing by matrix id.
// Round 2: LDS-aggregated histogram/scatter (kills same-address global-atomic
// serialization that cost ~120 us), convert fused into hist launch.

#define DD 128
#define NN 21845
#define NPOS 18
#define NDEP 46
#define NCH 21844   // total children over levels 0..6
#define NBUCKET 340 // 18 pos + 7*46 dep

typedef __attribute__((ext_vector_type(8))) short short8;
typedef __attribute__((ext_vector_type(4))) float f32x4;

__device__ __forceinline__ unsigned short f2bf(float f) {
    union { float f; unsigned int u; } v; v.f = f;
    unsigned int r = v.u + 0x7fffu + ((v.u >> 16) & 1u);   // RNE
    return (unsigned short)(r >> 16);
}
__device__ __forceinline__ float bf2f(unsigned short s) {
    union { unsigned int u; float f; } v; v.u = ((unsigned int)s) << 16;
    return v.f;
}

// decode flat child index j (0..NCH) -> level l, child local idx c, bucket
__device__ __forceinline__ void decode_child(int j, const int* __restrict__ dep_ids,
                                             int& l, int& c, int& b) {
    int base = 0, sz = 4;
    l = 0;
    while (j >= base + sz) { base += sz; sz <<= 2; ++l; }
    c = j - base;
    int did = dep_ids[base + 1 + c];          // ls[l+1] = base+1
    b = NPOS + l * NDEP + did;
}

// ---- fused: blocks 0..255 convert W (bf16, transposed); blocks 256.. hist ----
__global__ __launch_bounds__(256) void prep_kernel(
        const float* __restrict__ posW, const float* __restrict__ depW,
        unsigned short* __restrict__ Wt,
        const int* __restrict__ pos_ids, const int* __restrict__ dep_ids,
        int* __restrict__ cnt) {
    __shared__ char smem[64 * 72 * 2];
    if (blockIdx.x < 256) {
        unsigned short (*lds)[72] = (unsigned short (*)[72])smem;
        int mat = blockIdx.x >> 2;
        int tile = blockIdx.x & 3;
        int tk = (tile >> 1) * 64, tn = (tile & 1) * 64;
        const float* W = (mat < NPOS) ? (posW + (size_t)mat * DD * DD)
                                      : (depW + (size_t)(mat - NPOS) * DD * DD);
        unsigned short* O = Wt + (size_t)mat * DD * DD;
        int tx = threadIdx.x & 63, ty = threadIdx.x >> 6;
#pragma unroll
        for (int i = 0; i < 16; ++i) {
            int r = ty + i * 4;
            lds[tx][r] = f2bf(W[(size_t)(tk + r) * DD + tn + tx]);
        }
        __syncthreads();
#pragma unroll
        for (int i = 0; i < 16; ++i) {
            int r = ty + i * 4;
            O[(size_t)(tn + r) * DD + tk + tx] = lds[r][tx];
        }
    } else {
        int* h = (int*)smem;
        for (int i = threadIdx.x; i < NBUCKET; i += 256) h[i] = 0;
        __syncthreads();
        int g = (blockIdx.x - 256) * 256 + threadIdx.x;
        if (g < NN) {
            atomicAdd(&h[pos_ids[g]], 1);
        } else if (g < NN + NCH) {
            int l, c, b;
            decode_child(g - NN, dep_ids, l, c, b);
            atomicAdd(&h[b], 1);
        }
        __syncthreads();
        for (int i = threadIdx.x; i < NBUCKET; i += 256) {
            int v = h[i];
            if (v) atomicAdd(&cnt[i], v);
        }
    }
}

__global__ void scan_kernel(const int* __restrict__ cnt, int* __restrict__ cur,
                            int* __restrict__ ntiles, int2* __restrict__ tbl1,
                            int2* __restrict__ tblL) {
    int w = threadIdx.x >> 6;
    int lane = threadIdx.x & 63;
    if (lane != 0) return;
    if (w == 0) {
        int off = 0, t = 0;
        for (int b = 0; b < NPOS; ++b) {
            int c = cnt[b];
            cur[b] = off;
            for (int rs = 0; rs < c; rs += 64) {
                int rr = min(64, c - rs);
                tbl1[t].x = b | (rr << 8);
                tbl1[t].y = off + rs;
                ++t;
            }
            off += c;
        }
        ntiles[0] = t;
    } else {
        int l = w - 1;
        const int baseTab[7] = {0, 4, 20, 84, 340, 1364, 5460}; // ls[l+1]-1
        int base = baseTab[l];
        int off = 0, t = 0;
        int2* tb = tblL + l * 302;
        for (int b = 0; b < NDEP; ++b) {
            int c = cnt[NPOS + l * NDEP + b];
            cur[NPOS + l * NDEP + b] = base + off;
            for (int rs = 0; rs < c; rs += 64) {
                int rr = min(64, c - rs);
                tb[t].x = b | (rr << 8);
                tb[t].y = base + off + rs;
                ++t;
            }
            off += c;
        }
        ntiles[1 + l] = t;
    }
}

// ---- scatter with LDS-aggregated ranks: one global atomic per bucket/block ----
__global__ __launch_bounds__(256) void scatter_kernel(
        const int* __restrict__ pos_ids, const int* __restrict__ dep_ids,
        int* __restrict__ cur, int* __restrict__ perm_pos,
        int* __restrict__ perm_dep) {
    __shared__ int h[NBUCKET];
    __shared__ int base[NBUCKET];
    for (int i = threadIdx.x; i < NBUCKET; i += 256) h[i] = 0;
    __syncthreads();
    int g = blockIdx.x * 256 + threadIdx.x;
    int b = -1, payload = 0;
    if (g < NN) {
        b = pos_ids[g];
        payload = g;
    } else if (g < NN + NCH) {
        int l, c;
        decode_child(g - NN, dep_ids, l, c, b);
        payload = c;
    }
    int local = 0;
    if (b >= 0) local = atomicAdd(&h[b], 1);
    __syncthreads();
    for (int i = threadIdx.x; i < NBUCKET; i += 256) {
        int v = h[i];
        if (v) base[i] = atomicAdd(&cur[i], v);
    }
    __syncthreads();
    if (b >= 0) {
        int idx = base[b] + local;
        if (b < NPOS) perm_pos[idx] = payload;
        else perm_dep[idx] = payload;
    }
}

// ---------------- GEMM: 64-row tile x N=128, K=128, 4 waves ----------------
// MODE 0: A = bf16(emb[perm_pos[r]]), out = x_bf16[node]
// MODE 1: A = x_bf16[perm[r]] (xb pre-offset),   out = u[c]
// MODE 2: A = max(x_bf16[c], u_prev[4c+j]),      out = u[c]
template <int MODE>
__global__ __launch_bounds__(256) void gemm_kernel(
        const int2* __restrict__ tbl, const int* __restrict__ ntp,
        const int* __restrict__ perm, const unsigned short* __restrict__ Wt,
        const float* __restrict__ bias, const float* __restrict__ embf,
        const unsigned short* __restrict__ xb, const unsigned short* __restrict__ uprev,
        unsigned short* __restrict__ outr) {
    int nt = ntp[0];
    if ((int)blockIdx.x >= nt) return;
    int2 e = tbl[blockIdx.x];
    int bucket = e.x & 255;
    int rows = e.x >> 8;
    int rowstart = e.y;
    int lane = threadIdx.x & 63;
    int w = threadIdx.x >> 6;
    int lr = lane & 15;
    int kk = (lane >> 4) * 8;

    const short8 zero8 = {0, 0, 0, 0, 0, 0, 0, 0};

    int m_a = w * 16 + lr;
    bool valid_a = m_a < rows;
    int rid_a = valid_a ? perm[rowstart + m_a] : 0;

    short8 afr[4];
    if (MODE == 0) {
        const float* ar = embf + (size_t)rid_a * DD + kk;
#pragma unroll
        for (int s = 0; s < 4; ++s) {
            float4 lo = *(const float4*)(ar + s * 32);
            float4 hi = *(const float4*)(ar + s * 32 + 4);
            short8 a;
            a[0] = (short)f2bf(lo.x); a[1] = (short)f2bf(lo.y);
            a[2] = (short)f2bf(lo.z); a[3] = (short)f2bf(lo.w);
            a[4] = (short)f2bf(hi.x); a[5] = (short)f2bf(hi.y);
            a[6] = (short)f2bf(hi.z); a[7] = (short)f2bf(hi.w);
            afr[s] = valid_a ? a : zero8;
        }
    } else if (MODE == 1) {
        const unsigned short* ar = xb + (size_t)rid_a * DD + kk;
#pragma unroll
        for (int s = 0; s < 4; ++s)
            afr[s] = valid_a ? *(const short8*)(ar + s * 32) : zero8;
    } else {
        const unsigned short* xr = xb + (size_t)rid_a * DD + kk;
        const unsigned short* ur = uprev + (size_t)(4 * rid_a) * DD + kk;
#pragma unroll
        for (int s = 0; s < 4; ++s) {
            short8 a = *(const short8*)(xr + s * 32);
#pragma unroll
            for (int j = 0; j < 4; ++j) {
                short8 u = *(const short8*)(ur + j * DD + s * 32);
#pragma unroll
                for (int q = 0; q < 8; ++q)
                    if ((unsigned short)u[q] > (unsigned short)a[q]) a[q] = u[q];
            }
            afr[s] = valid_a ? a : zero8;
        }
    }

    f32x4 acc[8];
#pragma unroll
    for (int t = 0; t < 8; ++t) acc[t] = (f32x4){0.f, 0.f, 0.f, 0.f};

    const unsigned short* Wb = Wt + (size_t)bucket * DD * DD;
#pragma unroll
    for (int s = 0; s < 4; ++s) {
        short8 bfr[8];
#pragma unroll
        for (int t = 0; t < 8; ++t)
            bfr[t] = *(const short8*)(Wb + (size_t)(t * 16 + lr) * DD + s * 32 + kk);
#pragma unroll
        for (int t = 0; t < 8; ++t)
            acc[t] = __builtin_amdgcn_mfma_f32_16x16x32_bf16(afr[s], bfr[t], acc[t], 0, 0, 0);
    }

    int rq[4]; bool vq[4];
#pragma unroll
    for (int q = 0; q < 4; ++q) {
        int m = w * 16 + (lane >> 4) * 4 + q;
        vq[q] = m < rows;
        rq[q] = vq[q] ? perm[rowstart + m] : 0;
    }
    const float* bb = bias + bucket * DD;
#pragma unroll
    for (int t = 0; t < 8; ++t) {
        int col = t * 16 + lr;
        float bv = bb[col];
#pragma unroll
        for (int q = 0; q < 4; ++q) {
            if (vq[q]) {
                float v = fmaxf(acc[t][q] + bv, 0.f);
                outr[(size_t)rq[q] * DD + col] = f2bf(v);
            }
        }
    }
}

__global__ void final_kernel(const unsigned short* __restrict__ xb,
                             const unsigned short* __restrict__ u0,
                             float* __restrict__ out) {
    int e = threadIdx.x;
    unsigned short m = xb[e];
#pragma unroll
    for (int j = 0; j < 4; ++j) {
        unsigned short u = u0[j * DD + e];
        if (u > m) m = u;
    }
    out[e] = bf2f(m);
}

extern "C" void kernel_launch(void* const* d_in, const int* in_sizes, int n_in,
                              void* d_out, int out_size, void* d_ws, size_t ws_size,
                              hipStream_t stream) {
    const float* emb     = (const float*)d_in[0];
    const int*   pos_ids = (const int*)d_in[1];
    const int*   dep_ids = (const int*)d_in[2];
    const float* pos_W   = (const float*)d_in[3];
    const float* pos_b   = (const float*)d_in[4];
    const float* dep_W   = (const float*)d_in[5];
    const float* dep_b   = (const float*)d_in[6];
    float* out = (float*)d_out;

    char* p = (char*)d_ws;
    auto alloc = [&](size_t bytes) {
        char* r = p; p += (bytes + 255) & ~(size_t)255; return r;
    };
    unsigned short* xbf = (unsigned short*)alloc((size_t)NN * DD * 2);
    unsigned short* uA  = (unsigned short*)alloc((size_t)16384 * DD * 2);
    unsigned short* uB  = (unsigned short*)alloc((size_t)4096 * DD * 2);
    unsigned short* Wt  = (unsigned short*)alloc((size_t)64 * DD * DD * 2);
    int*  cnt      = (int*)alloc(NBUCKET * 4);
    int*  cur      = (int*)alloc(NBUCKET * 4);
    int*  ntiles   = (int*)alloc(8 * 4);
    int*  perm_pos = (int*)alloc((size_t)NN * 4);
    int*  perm_dep = (int*)alloc((size_t)NCH * 4);
    int2* tbl1     = (int2*)alloc(360 * 8);
    int2* tblL     = (int2*)alloc(7 * 302 * 8);

    hipMemsetAsync(cnt, 0, NBUCKET * 4, stream);
    prep_kernel<<<256 + 171, 256, 0, stream>>>(pos_W, dep_W, Wt, pos_ids, dep_ids, cnt);
    scan_kernel<<<1, 512, 0, stream>>>(cnt, cur, ntiles, tbl1, tblL);
    scatter_kernel<<<171, 256, 0, stream>>>(pos_ids, dep_ids, cur, perm_pos, perm_dep);

    gemm_kernel<0><<<360, 256, 0, stream>>>(tbl1, ntiles + 0, perm_pos, Wt, pos_b,
                                            emb, nullptr, nullptr, xbf);

    const unsigned short* Wtd = Wt + (size_t)NPOS * DD * DD;
    gemm_kernel<1><<<302, 256, 0, stream>>>(tblL + 6 * 302, ntiles + 7, perm_dep, Wtd,
                                            dep_b, nullptr, xbf + (size_t)5461 * DD,
                                            nullptr, uA);
    const int ls_c[7]  = {1, 5, 21, 85, 341, 1365, 5461};
    const int grids[7] = {4, 16, 47, 50, 62, 110, 302};
    unsigned short* uin = uA;
    unsigned short* uout = uB;
    for (int l = 5; l >= 0; --l) {
        gemm_kernel<2><<<grids[l], 256, 0, stream>>>(tblL + l * 302, ntiles + 1 + l,
                                                     perm_dep, Wtd, dep_b, nullptr,
                                                     xbf + (size_t)ls_c[l] * DD, uin, uout);
        unsigned short* t = uin; uin = uout; uout = t;
    }
    final_kernel<<<1, 128, 0, stream>>>(xbf, uin, out);
}